// Round 12
// baseline (269.361 us; speedup 1.0000x reference)
//
#include <hip/hip_runtime.h>
#include <cstdint>

// Fisher-Kolmogorov explicit Euler, B=2, 128^3, up to 40 masked micro-steps.
// Round-12: T=2 fusion with IN-PLACE LDS staging. Stage u region (8z x 12y x
// 128x, 48 KB) once; z-march step-1, overwriting su plane j with s1 plane j
// (race-free: plane-j writes are own-cell/row-disjoint from plane-j reads;
// barrier per plane protects plane j+1). Thread-owned z-columns keep s1
// center chain + interior (D,rho) q8 in registers. Eliminates R9's halo-ring
// global re-reads (100 KB/block) -> per-block requests 188->79 KB at
// 3 blocks/CU (12 waves/CU, vs R9's 16).
// Pre-registered: if >= 243.5 us, R9 is the structural floor -> declare.

constexpr int NX = 128, NY = 128, NZ = 128;
constexpr int PLANE = NX * NY;            // 16384
constexpr int VOL   = NZ * PLANE;         // 2,097,152
constexpr int TOTAL = 2 * VOL;            // 4,194,304
constexpr float DT  = 0.1f;               // MICRO_DT
constexpr int MAX_PAIRS = 20;             // 40 micro-steps / 2

constexpr int TY = 8, TZ = 4;             // block interior tile (x full 128)
constexpr int RY = TY + 2, RZ = TZ + 2;   // s1 region: 10 y x 6 z planes
constexpr int UY = TY + 4, UZ = TZ + 4;   // staged u region: 12 y x 8 z planes
constexpr int UREGION_F4 = UZ * UY * 32;  // 3072 (12 f4 loads/thread)
constexpr int BLOCKS = 2 * (NZ / TZ) * (NY / TY);  // 1024

__device__ __forceinline__ float4 ld4(const float* p) { return *(const float4*)p; }
__device__ __forceinline__ float clip01(float v) { return fminf(fmaxf(v, 0.0f), 1.0f); }

// 8-bit fixed-point (D,rho): lo byte = D/0.1*255, hi byte = rho/0.5*255.
__device__ __forceinline__ uint32_t packDR8(float Dv, float Rv) {
    const uint32_t dq = (uint32_t)fminf(fmaf(Dv, 2550.0f, 0.5f), 255.0f);
    const uint32_t rq = (uint32_t)fminf(fmaf(Rv, 510.0f, 0.5f), 255.0f);
    return dq | (rq << 8);
}
__device__ __forceinline__ float4 decD8(ushort4 v) {
    constexpr float s = 0.1f / 255.0f;
    return make_float4((float)(v.x & 0xff) * s, (float)(v.y & 0xff) * s,
                       (float)(v.z & 0xff) * s, (float)(v.w & 0xff) * s);
}
__device__ __forceinline__ float4 decR8(ushort4 v) {
    constexpr float s = 0.5f / 255.0f;
    return make_float4((float)(v.x >> 8) * s, (float)(v.y >> 8) * s,
                       (float)(v.z >> 8) * s, (float)(v.w >> 8) * s);
}

__device__ __forceinline__ float4 fkstep(float4 c, float xm, float xp,
                                         float4 ym, float4 yp,
                                         float4 zm, float4 zp,
                                         float4 Dv, float4 Rv) {
    float4 o;
    o.x = fmaf(DT, fmaf(Dv.x, (xm + c.y) + (ym.x + yp.x) + (zm.x + zp.x) - 6.0f * c.x,
                        Rv.x * c.x * (1.0f - c.x)), c.x);
    o.y = fmaf(DT, fmaf(Dv.y, (c.x + c.z) + (ym.y + yp.y) + (zm.y + zp.y) - 6.0f * c.y,
                        Rv.y * c.y * (1.0f - c.y)), c.y);
    o.z = fmaf(DT, fmaf(Dv.z, (c.y + c.w) + (ym.z + yp.z) + (zm.z + zp.z) - 6.0f * c.z,
                        Rv.z * c.z * (1.0f - c.z)), c.z);
    o.w = fmaf(DT, fmaf(Dv.w, (c.z + xp) + (ym.w + yp.w) + (zm.w + zp.w) - 6.0f * c.w,
                        Rv.w * c.w * (1.0f - c.w)), c.w);
    return o;
}

__global__ __launch_bounds__(256, 3)
void fk_pair(const float* __restrict__ src, float* __restrict__ dst0,
             float* __restrict__ out, const float* __restrict__ u0,
             const float* __restrict__ Dm, const float* __restrict__ Rm,
             unsigned short* __restrict__ dr8, const int* __restrict__ dtd, int p)
{
    const int b  = blockIdx.x >> 9;                  // batch item (block-uniform)
    int d = dtd[b]; d = d < 0 ? 0 : (d > 4 ? 4 : d);
    const int steps = d * 10;

    const int zb = (blockIdx.x >> 4) & 31;
    const int yt = blockIdx.x & 15;
    const int z0 = zb * TZ, y0 = yt * TY;
    const int tid = threadIdx.x;
    const int xq  = tid & 31;                        // float4 lane within row
    const int yi  = tid >> 5;                        // 0..7
    const int baseb = b << 21;
    const float4 zero = make_float4(0.f, 0.f, 0.f, 0.f);

    if (2 * p >= steps) {
        // d==0 items never get a step write: emit clip(u0) once, in pair 0.
        if (steps == 0 && p == 0) {
            #pragma unroll
            for (int k = 0; k < TZ; ++k) {
                const int idx = baseb + (z0 + k) * PLANE + (y0 + yi) * NX + (xq << 2);
                const float4 v = ld4(u0 + idx);
                float4 o;
                o.x = clip01(v.x); o.y = clip01(v.y);
                o.z = clip01(v.z); o.w = clip01(v.w);
                *(float4*)(out + idx) = o;
            }
        }
        return;                                      // block-uniform exit
    }
    const bool first = (p == 0);
    const bool last  = (2 * p == steps - 2);
    float* __restrict__ dst = last ? out : dst0;

    __shared__ float su[UZ * UY * NX];               // 48 KiB; planes reused for s1

    // ---- Phase 0: stage u region (each element once, coalesced, 0-padded) --
    #pragma unroll
    for (int it = 0; it < UREGION_F4 / 256; ++it) {  // 12
        const int i = tid + it * 256;
        const int cx = i & 31;
        const int r  = i >> 5;                       // 0..95
        const int uy = r % UY;
        const int uz = r / UY;
        const int y = y0 - 2 + uy;
        const int z = z0 - 2 + uz;
        float4 v = zero;                             // Dirichlet zero halo
        if ((unsigned)y < (unsigned)NY && (unsigned)z < (unsigned)NZ)
            v = ld4(src + baseb + z * PLANE + y * NX + (cx << 2));
        *(float4*)&su[r * NX + (cx << 2)] = v;
    }
    __syncthreads();

    // ---- Phase 1: step-1 z-march, in place. s1 plane j (z = z0-1+j) needs
    // su planes j, j+1, j+2; after computing, plane j is dead -> overwrite
    // slot j with s1 plane j. Own-cell z-chain in registers. ----
    float4  s1col[RZ];                               // own-column s1 values
    ushort4 pr4[TZ];                                 // interior (D,rho) q8
    const int y = y0 + yi;                           // primary y (in-domain)
    const int suRowP = yi + 2;                       // primary su row
    // extra cell (ring rows ry=0 / ry=9) handled by wave 0
    const int ery  = (tid < 32) ? 0 : (RY - 1);
    const int ecx  = tid & 31;
    const int eRow = ery + 1;                        // su row 1 or 10
    const int ey   = y0 - 1 + ery;                   // may be out of domain

    float4 uA = ld4(&su[(0 * UY + suRowP) * NX + (xq << 2)]);  // su[0] own
    float4 uB = ld4(&su[(1 * UY + suRowP) * NX + (xq << 2)]);  // su[1] own

    #pragma unroll
    for (int j = 0; j < RZ; ++j) {
        const int z = z0 - 1 + j;
        const bool zin = ((unsigned)z < (unsigned)NZ);   // block-uniform
        const float4 un = ld4(&su[((j + 2) * UY + suRowP) * NX + (xq << 2)]);

        // -- primary cell (ry = yi+1) --
        float4 o = zero;
        if (zin) {
            const float4 ym4 = ld4(&su[((j + 1) * UY + suRowP - 1) * NX + (xq << 2)]);
            const float4 yp4 = ld4(&su[((j + 1) * UY + suRowP + 1) * NX + (xq << 2)]);
            const float* rowc = &su[((j + 1) * UY + suRowP) * NX];
            const float xm = (xq > 0)  ? rowc[(xq << 2) - 1] : 0.0f;
            const float xp = (xq < 31) ? rowc[(xq << 2) + 4] : 0.0f;
            const int idx = baseb + z * PLANE + y * NX + (xq << 2);
            float4 Dv, Rv;
            if (first) {
                Dv = ld4(Dm + idx);
                Rv = ld4(Rm + idx);
                if (j >= 1 && j <= TZ) {             // block interior: publish
                    ushort4 pk;
                    pk.x = (unsigned short)packDR8(Dv.x, Rv.x);
                    pk.y = (unsigned short)packDR8(Dv.y, Rv.y);
                    pk.z = (unsigned short)packDR8(Dv.z, Rv.z);
                    pk.w = (unsigned short)packDR8(Dv.w, Rv.w);
                    *(ushort4*)(dr8 + idx) = pk;
                    pr4[j - 1] = pk;
                }
            } else {
                const ushort4 pk = *(const ushort4*)(dr8 + idx);
                if (j >= 1 && j <= TZ) pr4[j - 1] = pk;
                Dv = decD8(pk);
                Rv = decR8(pk);
            }
            o = fkstep(uB, xm, xp, ym4, yp4, uA, un, Dv, Rv);
        }
        s1col[j] = o;

        // -- extra ring cell (rows ry=0 and ry=9), wave 0 only --
        float4 oe = zero;
        if (tid < 64) {
            if (zin && (unsigned)ey < (unsigned)NY) {
                const float4 ec  = ld4(&su[((j + 1) * UY + eRow) * NX + (ecx << 2)]);
                const float4 ezm = ld4(&su[( j      * UY + eRow) * NX + (ecx << 2)]);
                const float4 ezp = ld4(&su[((j + 2) * UY + eRow) * NX + (ecx << 2)]);
                const float4 eym = ld4(&su[((j + 1) * UY + eRow - 1) * NX + (ecx << 2)]);
                const float4 eyp = ld4(&su[((j + 1) * UY + eRow + 1) * NX + (ecx << 2)]);
                const float* erow = &su[((j + 1) * UY + eRow) * NX];
                const float exm = (ecx > 0)  ? erow[(ecx << 2) - 1] : 0.0f;
                const float exp_ = (ecx < 31) ? erow[(ecx << 2) + 4] : 0.0f;
                const int eidx = baseb + z * PLANE + ey * NX + (ecx << 2);
                float4 Dv, Rv;
                if (first) {
                    Dv = ld4(Dm + eidx);
                    Rv = ld4(Rm + eidx);
                } else {
                    const ushort4 pk = *(const ushort4*)(dr8 + eidx);
                    Dv = decD8(pk);
                    Rv = decR8(pk);
                }
                oe = fkstep(ec, exm, exp_, eym, eyp, ezm, ezp, Dv, Rv);
            }
        }

        // -- writes into slot j (disjoint/own-cell vs all plane-j reads) --
        *(float4*)&su[(j * UY + suRowP) * NX + (xq << 2)] = o;
        if (tid < 64)
            *(float4*)&su[(j * UY + eRow) * NX + (ecx << 2)] = oe;

        __syncthreads();                             // protect plane j+1
        uA = uB; uB = un;
    }

    // ---- Phase 2: step-2 interior. Center z-chain + dr from registers;
    // y/x laterals from the s1 slots. ----
    #pragma unroll
    for (int k = 0; k < TZ; ++k) {
        const int slot = k + 1;
        const float4 ym4 = ld4(&su[(slot * UY + yi + 1) * NX + (xq << 2)]);
        const float4 yp4 = ld4(&su[(slot * UY + yi + 3) * NX + (xq << 2)]);
        const float* rowc = &su[(slot * UY + yi + 2) * NX];
        const float xm = (xq > 0)  ? rowc[(xq << 2) - 1] : 0.0f;
        const float xp = (xq < 31) ? rowc[(xq << 2) + 4] : 0.0f;

        float4 o = fkstep(s1col[k + 1], xm, xp, ym4, yp4,
                          s1col[k], s1col[k + 2],
                          decD8(pr4[k]), decR8(pr4[k]));
        if (last) {
            o.x = clip01(o.x); o.y = clip01(o.y);
            o.z = clip01(o.z); o.w = clip01(o.w);
        }
        const int idx = baseb + (z0 + k) * PLANE + y * NX + (xq << 2);
        *(float4*)(dst + idx) = o;
    }
}

extern "C" void kernel_launch(void* const* d_in, const int* in_sizes, int n_in,
                              void* d_out, int out_size, void* d_ws, size_t ws_size,
                              hipStream_t stream) {
    const float* u0  = (const float*)d_in[0];
    const float* Dm  = (const float*)d_in[1];
    const float* Rm  = (const float*)d_in[2];
    const int*   dtd = (const int*)d_in[3];
    float* out = (float*)d_out;
    float* ws  = (float*)d_ws;
    // ws layout: [0,16M) buf0, [16M,32M) buf1, [32M,40M) q8 DR (ws=256MB).
    float* buf[2] = { ws, ws + TOTAL };
    unsigned short* dr8 = (unsigned short*)(ws + 2 * TOTAL);

    // Pair p advances steps 2p,2p+1. src: u0 for p=0 else buf[(p-1)&1];
    // normal dst alternates buf[p&1]; an item's LAST pair redirects to `out`
    // (clipped) on-device. d==0 items emit clip(u0) during pair 0.
    for (int p = 0; p < MAX_PAIRS; ++p) {
        const float* src = (p == 0) ? u0 : buf[(p - 1) & 1];
        fk_pair<<<BLOCKS, 256, 0, stream>>>(src, buf[p & 1], out, u0,
                                            Dm, Rm, dr8, dtd, p);
    }
}

// Round 13
// 243.835 us; speedup vs baseline: 1.1047x; 1.1047x over previous
//
#include <hip/hip_runtime.h>
#include <cstdint>

// Fisher-Kolmogorov explicit Euler, B=2, 128^3, up to 40 masked micro-steps.
// FINAL (= round-9 kernel, best of 13 rounds at 243.5 us):
//   - 20 graph-captured fk_pair dispatches, each fusing 2 micro-steps
//     (T=2 temporal fusion; steps=10*d is even so pair masks are uniform)
//   - 8y x 4z x 128x tile, 1024 blocks, 30 KB LDS, 4 blocks/CU = 16 waves/CU
//     (occupancy empirically dominates: 16 waves/CU beats every lower-wave
//      variant regardless of byte savings -- R6/R7/R12)
//   - phase 1a computes step-1 interior with the phase-2 thread map, carrying
//     packed bf16 (D,rho) in registers; phase 1b does the 28-row halo ring;
//     phase 2 computes step-2 from LDS s1 (z-rolled registers)
//   - final pair per item writes clipped output directly to d_out (on-device
//     "last" detection); d==0 items emit clip(u0) during pair 0
// Measured: active pairs ~5.4 TB/s effective (~86% of 6.3 TB/s achievable),
// i.e. the both-active dispatches are at the memory roofline; residual is
// single-active/empty dispatch latency that cheaper sync cannot express
// (cooperative grid.sync measured 15x worse, R1).

constexpr int NX = 128, NY = 128, NZ = 128;
constexpr int PLANE = NX * NY;            // 16384
constexpr int VOL   = NZ * PLANE;         // 2,097,152
constexpr int TOTAL = 2 * VOL;            // 4,194,304
constexpr float DT  = 0.1f;               // MICRO_DT
constexpr int MAX_PAIRS = 20;             // 40 micro-steps / 2

constexpr int TY = 8, TZ = 4;             // block interior tile (x full 128)
constexpr int RY = TY + 2, RZ = TZ + 2;   // s1 region: 10 y x 6 z
constexpr int RING_ROWS = RZ * RY - TZ * TY;       // 28
constexpr int RING_F4   = RING_ROWS * 32;          // 896
constexpr int BLOCKS = 2 * (NZ / TZ) * (NY / TY);  // 2*32*16 = 1024

__device__ __forceinline__ float4 ld4(const float* p) { return *(const float4*)p; }

__device__ __forceinline__ uint32_t f2bf(float f) {
    uint32_t u = __float_as_uint(f);
    u += 0x7fffu + ((u >> 16) & 1u);      // round-to-nearest-even
    return u >> 16;
}
__device__ __forceinline__ float bf_lo(uint32_t p) { return __uint_as_float(p << 16); }
__device__ __forceinline__ float bf_hi(uint32_t p) { return __uint_as_float(p & 0xffff0000u); }
__device__ __forceinline__ float clip01(float v) { return fminf(fmaxf(v, 0.0f), 1.0f); }

__device__ __forceinline__ float4 fkstep(float4 c, float xm, float xp,
                                         float4 ym, float4 yp,
                                         float4 zm, float4 zp,
                                         float4 Dv, float4 Rv) {
    float4 o;
    o.x = fmaf(DT, fmaf(Dv.x, (xm + c.y) + (ym.x + yp.x) + (zm.x + zp.x) - 6.0f * c.x,
                        Rv.x * c.x * (1.0f - c.x)), c.x);
    o.y = fmaf(DT, fmaf(Dv.y, (c.x + c.z) + (ym.y + yp.y) + (zm.y + zp.y) - 6.0f * c.y,
                        Rv.y * c.y * (1.0f - c.y)), c.y);
    o.z = fmaf(DT, fmaf(Dv.z, (c.y + c.w) + (ym.z + yp.z) + (zm.z + zp.z) - 6.0f * c.z,
                        Rv.z * c.z * (1.0f - c.z)), c.z);
    o.w = fmaf(DT, fmaf(Dv.w, (c.z + xp) + (ym.w + yp.w) + (zm.w + zp.w) - 6.0f * c.w,
                        Rv.w * c.w * (1.0f - c.w)), c.w);
    return o;
}

__device__ __forceinline__ float4 unpackD(uint4 p) {
    return make_float4(bf_lo(p.x), bf_lo(p.y), bf_lo(p.z), bf_lo(p.w));
}
__device__ __forceinline__ float4 unpackR(uint4 p) {
    return make_float4(bf_hi(p.x), bf_hi(p.y), bf_hi(p.z), bf_hi(p.w));
}

__global__ __launch_bounds__(256, 4)
void fk_pair(const float* __restrict__ src, float* __restrict__ dst0,
             float* __restrict__ out, const float* __restrict__ u0,
             const float* __restrict__ Dm, const float* __restrict__ Rm,
             uint32_t* __restrict__ dr, const int* __restrict__ dtd, int p)
{
    const int b  = blockIdx.x >> 9;                  // batch item (block-uniform)
    int d = dtd[b]; d = d < 0 ? 0 : (d > 4 ? 4 : d);
    const int steps = d * 10;

    const int zb = (blockIdx.x >> 4) & 31;
    const int yt = blockIdx.x & 15;
    const int z0 = zb * TZ, y0 = yt * TY;
    const int tid = threadIdx.x;
    const int xq  = tid & 31;                        // float4 lane within row
    const int yi  = tid >> 5;                        // 0..7
    const int baseb = b << 21;
    const float4 zero = make_float4(0.f, 0.f, 0.f, 0.f);

    if (2 * p >= steps) {
        // d==0 items never get a step write: emit clip(u0) once, in pair 0.
        if (steps == 0 && p == 0) {
            #pragma unroll
            for (int k = 0; k < TZ; ++k) {
                const int idx = baseb + (z0 + k) * PLANE + (y0 + yi) * NX + (xq << 2);
                const float4 v = ld4(u0 + idx);
                float4 o;
                o.x = clip01(v.x); o.y = clip01(v.y);
                o.z = clip01(v.z); o.w = clip01(v.w);
                *(float4*)(out + idx) = o;
            }
        }
        return;                                      // block-uniform exit
    }
    const bool first = (p == 0);
    const bool last  = (2 * p == steps - 2);
    float* __restrict__ dst = last ? out : dst0;

    __shared__ float s1[RZ * RY * NX];               // 30 KiB step-1 region

    // ---- Phase 1a: step-1 on the INTERIOR (same thread->cell map as phase
    // 2); packed dr carried in registers; z-rolled center planes. ----
    uint4 pr[TZ];                                    // 16 VGPRs of (D,rho) bf16
    {
        const int y = y0 + yi;                       // in-domain by construction
        const int colbase = baseb + y * NX + (xq << 2);
        const bool has_ym = (y > 0), has_yp = (y < NY - 1);
        const bool has_l = (xq > 0), has_r = (xq < 31);

        float4 um = (z0 > 0) ? ld4(src + colbase + (z0 - 1) * PLANE) : zero;
        float4 uc = ld4(src + colbase + z0 * PLANE);
        #pragma unroll
        for (int k = 0; k < TZ; ++k) {
            const int z = z0 + k;
            const int idx = colbase + z * PLANE;
            const float4 un = (z < NZ - 1) ? ld4(src + idx + PLANE) : zero;
            const float4 ym4 = has_ym ? ld4(src + idx - NX) : zero;
            const float4 yp4 = has_yp ? ld4(src + idx + NX) : zero;
            const float xm = has_l ? src[idx - 1] : 0.0f;
            const float xp = has_r ? src[idx + 4] : 0.0f;
            float4 Dv, Rv;
            if (first) {
                Dv = ld4(Dm + idx);
                Rv = ld4(Rm + idx);
                uint4 pk;
                pk.x = f2bf(Dv.x) | (f2bf(Rv.x) << 16);
                pk.y = f2bf(Dv.y) | (f2bf(Rv.y) << 16);
                pk.z = f2bf(Dv.z) | (f2bf(Rv.z) << 16);
                pk.w = f2bf(Dv.w) | (f2bf(Rv.w) << 16);
                *(uint4*)(dr + idx) = pk;            // publish for pairs >= 1
                pr[k] = pk;
            } else {
                pr[k] = *(const uint4*)(dr + idx);
                Dv = unpackD(pr[k]);
                Rv = unpackR(pr[k]);
            }
            const float4 o = fkstep(uc, xm, xp, ym4, yp4, um, un, Dv, Rv);
            *(float4*)&s1[((k + 1) * RY + (yi + 1)) * NX + (xq << 2)] = o;
            um = uc; uc = un;
        }
    }

    // ---- Phase 1b: step-1 on the 28-row halo ring (global loads) ----
    for (int i = tid; i < RING_F4; i += 256) {
        const int cxq = i & 31;
        const int r   = i >> 5;                      // ring row 0..27
        int rz, ry;
        if (r < 10)      { rz = 0; ry = r; }
        else if (r < 20) { rz = 5; ry = r - 10; }
        else { const int q = r - 20; rz = 1 + (q >> 1); ry = (q & 1) ? 9 : 0; }
        const int y = y0 - 1 + ry;
        const int z = z0 - 1 + rz;
        float4 o = zero;                             // out-of-domain -> 0
        if ((unsigned)y < (unsigned)NY && (unsigned)z < (unsigned)NZ) {
            const int idx = baseb + z * PLANE + y * NX + (cxq << 2);
            const float4 c  = ld4(src + idx);
            const float xm  = (cxq > 0)  ? src[idx - 1] : 0.0f;
            const float xp  = (cxq < 31) ? src[idx + 4] : 0.0f;
            const float4 ym4 = (y > 0)      ? ld4(src + idx - NX)    : zero;
            const float4 yp4 = (y < NY - 1) ? ld4(src + idx + NX)    : zero;
            const float4 zm4 = (z > 0)      ? ld4(src + idx - PLANE) : zero;
            const float4 zp4 = (z < NZ - 1) ? ld4(src + idx + PLANE) : zero;
            float4 Dv, Rv;
            if (first) {
                Dv = ld4(Dm + idx);
                Rv = ld4(Rm + idx);
            } else {
                const uint4 pk = *(const uint4*)(dr + idx);
                Dv = unpackD(pk);
                Rv = unpackR(pk);
            }
            o = fkstep(c, xm, xp, ym4, yp4, zm4, zp4, Dv, Rv);
        }
        *(float4*)&s1[(rz * RY + ry) * NX + (cxq << 2)] = o;
    }
    __syncthreads();

    // ---- Phase 2: step-2 on the interior from LDS s1; dr from registers;
    // x-neighbors via LDS f4-extracts; z-rolled s1 planes. ----
    {
        const int ry = yi + 1;
        const int y  = y0 + yi;
        float4 zmv = *(const float4*)&s1[(0 * RY + ry) * NX + (xq << 2)];
        float4 cv  = *(const float4*)&s1[(1 * RY + ry) * NX + (xq << 2)];
        #pragma unroll
        for (int k = 0; k < TZ; ++k) {
            const int rz = k + 1;
            const float4 zpv = *(const float4*)&s1[((rz + 1) * RY + ry) * NX + (xq << 2)];
            const float* rowc = &s1[(rz * RY + ry) * NX];
            float xm = 0.0f, xp = 0.0f;
            if (xq > 0)  xm = ((const float4*)&rowc[(xq - 1) << 2])->w;
            if (xq < 31) xp = ((const float4*)&rowc[(xq + 1) << 2])->x;
            const float4 ym4 = *(const float4*)&s1[(rz * RY + ry - 1) * NX + (xq << 2)];
            const float4 yp4 = *(const float4*)&s1[(rz * RY + ry + 1) * NX + (xq << 2)];

            float4 o = fkstep(cv, xm, xp, ym4, yp4, zmv, zpv,
                              unpackD(pr[k]), unpackR(pr[k]));
            if (last) {
                o.x = clip01(o.x); o.y = clip01(o.y);
                o.z = clip01(o.z); o.w = clip01(o.w);
            }
            const int idx = baseb + (z0 + k) * PLANE + y * NX + (xq << 2);
            *(float4*)(dst + idx) = o;
            zmv = cv; cv = zpv;
        }
    }
}

extern "C" void kernel_launch(void* const* d_in, const int* in_sizes, int n_in,
                              void* d_out, int out_size, void* d_ws, size_t ws_size,
                              hipStream_t stream) {
    const float* u0  = (const float*)d_in[0];
    const float* Dm  = (const float*)d_in[1];
    const float* Rm  = (const float*)d_in[2];
    const int*   dtd = (const int*)d_in[3];
    float* out = (float*)d_out;
    float* ws  = (float*)d_ws;
    // ws layout: [0,16M) buf0, [16M,32M) buf1, [32M,48M) packed DR (ws=256MB).
    float* buf[2] = { ws, ws + TOTAL };
    uint32_t* dr = (uint32_t*)(ws + 2 * TOTAL);

    // Pair p advances steps 2p,2p+1. src: u0 for p=0 else buf[(p-1)&1];
    // normal dst alternates buf[p&1]; an item's LAST pair redirects to `out`
    // (clipped) on-device. d==0 items emit clip(u0) during pair 0.
    for (int p = 0; p < MAX_PAIRS; ++p) {
        const float* src = (p == 0) ? u0 : buf[(p - 1) & 1];
        fk_pair<<<BLOCKS, 256, 0, stream>>>(src, buf[p & 1], out, u0,
                                            Dm, Rm, dr, dtd, p);
    }
}